// Round 1
// baseline (470.486 us; speedup 1.0000x reference)
//
#include <hip/hip_runtime.h>

#define DIN 128
#define DG 64

// ---------- K1: per-row degree + slot capture ----------
__global__ void k_deg(const int* __restrict__ rows, int* __restrict__ deg,
                      int* __restrict__ slot, int E) {
    int e = blockIdx.x * blockDim.x + threadIdx.x;
    if (e < E) slot[e] = atomicAdd(&deg[rows[e]], 1);
}

// ---------- K2: exclusive scan over deg[0..n) -> rowptr[0..n], single block ----------
__global__ void k_scan(const int* __restrict__ deg, int* __restrict__ rowptr, int n) {
    __shared__ int wsum[16];
    __shared__ int woff[16];
    int tid = threadIdx.x;
    int lane = tid & 63, w = tid >> 6;
    int carry = 0;
    for (int base = 0; base < n; base += 1024) {
        int i = base + tid;
        int v = (i < n) ? deg[i] : 0;
        int x = v;
        #pragma unroll
        for (int off = 1; off < 64; off <<= 1) {
            int y = __shfl_up(x, off, 64);
            if (lane >= off) x += y;
        }
        if (lane == 63) wsum[w] = x;
        __syncthreads();
        if (w == 0) {
            int t = (lane < 16) ? wsum[lane] : 0;
            int xx = t;
            #pragma unroll
            for (int off = 1; off < 16; off <<= 1) {
                int y = __shfl_up(xx, off, 64);
                if (lane >= off) xx += y;
            }
            if (lane < 16) woff[lane] = xx - t;  // exclusive
        }
        __syncthreads();
        int incl = x + woff[w];
        if (i < n) rowptr[i] = carry + incl - v;  // exclusive scan
        carry += woff[15] + wsum[15];
        __syncthreads();
    }
    if (tid == 0) rowptr[n] = carry;
}

// ---------- K3: scatter edge ids into CSR order ----------
__global__ void k_scatter(const int* __restrict__ rows, const int* __restrict__ rowptr,
                          const int* __restrict__ slot, int* __restrict__ edge_idx, int E) {
    int e = blockIdx.x * blockDim.x + threadIdx.x;
    if (e < E) edge_idx[rowptr[rows[e]] + slot[e]] = e;
}

// ---------- K4: fused GEMM  h0=relu(feat@W0+b0), h1=relu(feat@W1+b1), zj=feat@Wp ----------
#define MT 32
#define CT 64
__global__ __launch_bounds__(256) void k_gemm(
    const float* __restrict__ feat,
    const float* __restrict__ W0, const float* __restrict__ b0,
    const float* __restrict__ W1, const float* __restrict__ b1,
    const float* __restrict__ Wp,
    float* __restrict__ h0, float* __restrict__ h1, float* __restrict__ zj, int N) {
    __shared__ float As[128][MT + 1];  // [k][m], pad -> bank (k+m)%32
    __shared__ float Bs[128][CT];      // [k][n]
    int m0 = blockIdx.x * MT;
    int g  = blockIdx.y;  // 0,1 -> W0 halves; 2,3 -> W1 halves; 4 -> W_pool
    const float* Bsrc; int ldb; int cb;
    if (g < 2)      { Bsrc = W0; ldb = 128; cb = g * 64; }
    else if (g < 4) { Bsrc = W1; ldb = 128; cb = (g - 2) * 64; }
    else            { Bsrc = Wp; ldb = 64;  cb = 0; }
    int tid = threadIdx.x;
    for (int i = tid; i < MT * 128; i += 256) {
        int k = i & 127, m = i >> 7;
        int node = m0 + m;
        As[k][m] = (node < N) ? feat[(size_t)node * 128 + k] : 0.f;
    }
    for (int i = tid; i < CT * 128; i += 256) {
        int n = i & (CT - 1), k = i >> 6;
        Bs[k][n] = Bsrc[k * ldb + cb + n];
    }
    __syncthreads();
    int tx = tid & 15, ty = tid >> 4;  // tx: node pair, ty: 4-col group
    float acc[2][4] = {};
    #pragma unroll 8
    for (int k = 0; k < 128; ++k) {
        float a0 = As[k][tx * 2], a1 = As[k][tx * 2 + 1];
        float q0 = Bs[k][ty * 4], q1 = Bs[k][ty * 4 + 1];
        float q2 = Bs[k][ty * 4 + 2], q3 = Bs[k][ty * 4 + 3];
        acc[0][0] += a0 * q0; acc[0][1] += a0 * q1; acc[0][2] += a0 * q2; acc[0][3] += a0 * q3;
        acc[1][0] += a1 * q0; acc[1][1] += a1 * q1; acc[1][2] += a1 * q2; acc[1][3] += a1 * q3;
    }
    #pragma unroll
    for (int im = 0; im < 2; ++im) {
        int node = m0 + tx * 2 + im;
        if (node >= N) continue;
        #pragma unroll
        for (int j = 0; j < 4; ++j) {
            int c = g * 64 + ty * 4 + j;
            float v = acc[im][j];
            if (c < 128)      { v += b0[c];       v = fmaxf(v, 0.f); h0[(size_t)node * 128 + c] = v; }
            else if (c < 256) { int cc = c - 128; v += b1[cc]; v = fmaxf(v, 0.f); h1[(size_t)node * 128 + cc] = v; }
            else              { zj[(size_t)node * 64 + (c - 256)] = v; }
        }
    }
}

// ---------- K4b: per-node reductions: a_self, a_neigh, gpart ----------
__global__ __launch_bounds__(256) void k_node_red(
    const float* __restrict__ feat, const float* __restrict__ h0, const float* __restrict__ h1,
    const float* __restrict__ att, const float* __restrict__ Wg,
    float* __restrict__ a_self, float* __restrict__ a_neigh, float* __restrict__ gpart, int N) {
    int r = blockIdx.x * 4 + (threadIdx.x >> 6);
    int lane = threadIdx.x & 63;
    if (r >= N) return;
    float2 f  = ((const float2*)(feat + (size_t)r * 128))[lane];
    float2 x0 = ((const float2*)(h0 + (size_t)r * 128))[lane];
    float2 x1 = ((const float2*)(h1 + (size_t)r * 128))[lane];
    float2 A0 = ((const float2*)att)[lane];
    float2 A1 = ((const float2*)(att + 128))[lane];
    float2 G  = ((const float2*)Wg)[lane];
    float s0 = x0.x * A0.x + x0.y * A0.y;
    float s1 = x1.x * A1.x + x1.y * A1.y;
    float s2 = f.x * G.x + f.y * G.y;
    #pragma unroll
    for (int off = 32; off; off >>= 1) {
        s0 += __shfl_xor(s0, off, 64);
        s1 += __shfl_xor(s1, off, 64);
        s2 += __shfl_xor(s2, off, 64);
    }
    if (lane == 0) {
        a_self[r]  = (s0 >= 0.f) ? s0 : 0.2f * s0;
        a_neigh[r] = (s1 >= 0.f) ? s1 : 0.2f * s1;
        gpart[r]   = s2;
    }
}

// ---------- K5: per-row CSR aggregation + gate + dual batch-norm + sum ----------
__global__ __launch_bounds__(256) void k_aggregate(
    const int* __restrict__ cols, const float* __restrict__ vals,
    const int* __restrict__ rowptr, const int* __restrict__ edge_idx,
    const float* __restrict__ feat, const float* __restrict__ h0,
    const float* __restrict__ h1, const float* __restrict__ zj,
    const float* __restrict__ a_self, const float* __restrict__ a_neigh,
    const float* __restrict__ gpart, const float* __restrict__ Wg,
    const float* __restrict__ scale0, const float* __restrict__ offset0,
    const float* __restrict__ scale1, const float* __restrict__ offset1,
    float* __restrict__ out, int N) {
    int r = blockIdx.x * 4 + (threadIdx.x >> 6);
    int lane = threadIdx.x & 63;
    if (r >= N) return;
    int jb = rowptr[r], je = rowptr[r + 1];
    float2 accm = {0.f, 0.f}, acca = {0.f, 0.f};
    float zmax = -__builtin_inff();
    float asr = a_self[r];
    for (int j = jb; j < je; ++j) {
        int e = edge_idx[j];
        int c = cols[e];
        float v = vals[e];
        float es = asr + a_neigh[c];
        float2 f = ((const float2*)(feat + (size_t)c * 128))[lane];
        float2 h = ((const float2*)(h1 + (size_t)c * 128))[lane];
        float z = zj[(size_t)c * 64 + lane];
        accm.x += v * f.x;  accm.y += v * f.y;
        acca.x += es * h.x; acca.y += es * h.y;
        zmax = fmaxf(zmax, z);
    }
    if (jb == je) zmax = 0.f;  // empty segment: -inf -> 0
    // gate = gpart + zmax . Wg[128:192] + accm . Wg[192:320]
    float2 G2 = ((const float2*)(Wg + 192))[lane];
    float gs = zmax * Wg[128 + lane] + accm.x * G2.x + accm.y * G2.y;
    #pragma unroll
    for (int off = 32; off; off >>= 1) gs += __shfl_xor(gs, off, 64);
    float gate = gpart[r] + gs;
    float2 ag = {acca.x * gate, acca.y * gate};
    // BN on h0 row (two-pass: mean, then var)
    float2 x0 = ((const float2*)(h0 + (size_t)r * 128))[lane];
    float m0s = x0.x + x0.y;
    #pragma unroll
    for (int off = 32; off; off >>= 1) m0s += __shfl_xor(m0s, off, 64);
    float m0 = m0s * (1.f / 128.f);
    float d0x = x0.x - m0, d0y = x0.y - m0;
    float v0s = d0x * d0x + d0y * d0y;
    #pragma unroll
    for (int off = 32; off; off >>= 1) v0s += __shfl_xor(v0s, off, 64);
    float inv0 = rsqrtf(v0s * (1.f / 128.f) + 1e-9f);
    // BN on gated aggregation
    float m1s = ag.x + ag.y;
    #pragma unroll
    for (int off = 32; off; off >>= 1) m1s += __shfl_xor(m1s, off, 64);
    float m1 = m1s * (1.f / 128.f);
    float d1x = ag.x - m1, d1y = ag.y - m1;
    float v1s = d1x * d1x + d1y * d1y;
    #pragma unroll
    for (int off = 32; off; off >>= 1) v1s += __shfl_xor(v1s, off, 64);
    float inv1 = rsqrtf(v1s * (1.f / 128.f) + 1e-9f);
    float2 sc0 = ((const float2*)scale0)[lane], of0 = ((const float2*)offset0)[lane];
    float2 sc1 = ((const float2*)scale1)[lane], of1 = ((const float2*)offset1)[lane];
    float2 o;
    o.x = d0x * sc0.x * inv0 + of0.x + d1x * sc1.x * inv1 + of1.x;
    o.y = d0y * sc0.y * inv0 + of0.y + d1y * sc1.y * inv1 + of1.y;
    ((float2*)(out + (size_t)r * 128))[lane] = o;
}

extern "C" void kernel_launch(void* const* d_in, const int* in_sizes, int n_in,
                              void* d_out, int out_size, void* d_ws, size_t ws_size,
                              hipStream_t stream) {
    const int*   rows   = (const int*)d_in[0];
    const int*   cols   = (const int*)d_in[1];
    const float* vals   = (const float*)d_in[2];
    const float* feat   = (const float*)d_in[3];
    const float* W0     = (const float*)d_in[4];
    const float* b0     = (const float*)d_in[5];
    const float* W1     = (const float*)d_in[6];
    const float* b1     = (const float*)d_in[7];
    const float* att    = (const float*)d_in[8];
    const float* Wp     = (const float*)d_in[9];
    const float* Wg     = (const float*)d_in[10];
    const float* offset0 = (const float*)d_in[11];
    const float* scale0  = (const float*)d_in[12];
    const float* offset1 = (const float*)d_in[13];
    const float* scale1  = (const float*)d_in[14];
    float* out = (float*)d_out;

    const int E = in_sizes[0];
    const int N = in_sizes[3] / DIN;

    char* ws = (char*)d_ws;
    float* h0      = (float*)ws; ws += (size_t)N * 128 * sizeof(float);
    float* h1      = (float*)ws; ws += (size_t)N * 128 * sizeof(float);
    float* zj      = (float*)ws; ws += (size_t)N * 64 * sizeof(float);
    float* a_self  = (float*)ws; ws += (size_t)N * sizeof(float);
    float* a_neigh = (float*)ws; ws += (size_t)N * sizeof(float);
    float* gpart   = (float*)ws; ws += (size_t)N * sizeof(float);
    int* deg      = (int*)ws; ws += (size_t)(N + 1) * sizeof(int);
    int* rowptr   = (int*)ws; ws += (size_t)(N + 1) * sizeof(int);
    int* slot     = (int*)ws; ws += (size_t)E * sizeof(int);
    int* edge_idx = (int*)ws; ws += (size_t)E * sizeof(int);

    hipMemsetAsync(deg, 0, (size_t)(N + 1) * sizeof(int), stream);

    k_deg<<<(E + 255) / 256, 256, 0, stream>>>(rows, deg, slot, E);
    k_scan<<<1, 1024, 0, stream>>>(deg, rowptr, N);
    k_scatter<<<(E + 255) / 256, 256, 0, stream>>>(rows, rowptr, slot, edge_idx, E);

    dim3 gg((N + MT - 1) / MT, 5);
    k_gemm<<<gg, 256, 0, stream>>>(feat, W0, b0, W1, b1, Wp, h0, h1, zj, N);

    int nb4 = (N + 3) / 4;
    k_node_red<<<nb4, 256, 0, stream>>>(feat, h0, h1, att, Wg, a_self, a_neigh, gpart, N);
    k_aggregate<<<nb4, 256, 0, stream>>>(cols, vals, rowptr, edge_idx, feat, h0, h1, zj,
                                         a_self, a_neigh, gpart, Wg,
                                         scale0, offset0, scale1, offset1, out, N);
}

// Round 2
// 380.766 us; speedup vs baseline: 1.2356x; 1.2356x over previous
//
#include <hip/hip_runtime.h>

#define DIN 128
#define DG 64

// ---------- K1: per-row degree + slot capture ----------
__global__ void k_deg(const int* __restrict__ rows, int* __restrict__ deg,
                      int* __restrict__ slot, int E) {
    int e = blockIdx.x * blockDim.x + threadIdx.x;
    if (e < E) slot[e] = atomicAdd(&deg[rows[e]], 1);
}

// ---------- K2a: per-block exclusive scan (1024 elems/block) ----------
__global__ __launch_bounds__(1024) void k_scan1(const int* __restrict__ deg,
                                                int* __restrict__ rowptr,
                                                int* __restrict__ bsum, int n) {
    __shared__ int wsum[16];
    __shared__ int woff[16];
    int tid = threadIdx.x;
    int lane = tid & 63, w = tid >> 6;
    int i = blockIdx.x * 1024 + tid;
    int v = (i < n) ? deg[i] : 0;
    int x = v;
    #pragma unroll
    for (int off = 1; off < 64; off <<= 1) {
        int y = __shfl_up(x, off, 64);
        if (lane >= off) x += y;
    }
    if (lane == 63) wsum[w] = x;
    __syncthreads();
    if (w == 0) {
        int t = (lane < 16) ? wsum[lane] : 0;
        int xx = t;
        #pragma unroll
        for (int off = 1; off < 16; off <<= 1) {
            int y = __shfl_up(xx, off, 64);
            if (lane >= off) xx += y;
        }
        if (lane < 16) woff[lane] = xx - t;  // exclusive
    }
    __syncthreads();
    if (i < n) rowptr[i] = x - v + woff[w];
    if (tid == 1023) bsum[blockIdx.x] = woff[15] + wsum[15];
}

// ---------- K2b: scan of block sums (single wave, nb<=64) ----------
__global__ void k_scan2(const int* __restrict__ bsum, int* __restrict__ boff,
                        int* __restrict__ rowptr, int nb, int n) {
    int lane = threadIdx.x;
    int v = (lane < nb) ? bsum[lane] : 0;
    int x = v;
    #pragma unroll
    for (int off = 1; off < 64; off <<= 1) {
        int y = __shfl_up(x, off, 64);
        if (lane >= off) x += y;
    }
    boff[lane] = x - v;
    if (lane == 63) rowptr[n] = x;  // grand total
}

// ---------- K2c: add block offsets ----------
__global__ void k_scan3(int* __restrict__ rowptr, const int* __restrict__ boff, int n) {
    int i = blockIdx.x * blockDim.x + threadIdx.x;
    if (i < n) rowptr[i] += boff[i >> 10];
}

// ---------- K3: scatter edge ids into CSR order ----------
__global__ void k_scatter(const int* __restrict__ rows, const int* __restrict__ rowptr,
                          const int* __restrict__ slot, int* __restrict__ edge_idx, int E) {
    int e = blockIdx.x * blockDim.x + threadIdx.x;
    if (e < E) edge_idx[rowptr[rows[e]] + slot[e]] = e;
}

// ---------- K4: GEMM  out[N,TN] = act(feat[N,128] @ B[128,TN] + bias) ----------
// block tile 128 x TN, thread tile 8 x TTN; per-thread nodes {4tx..4tx+3, 64+4tx..67+4tx}
#define AS_LD 132
template<int TN, int TTN, bool RELU>
__global__ __launch_bounds__(256) void k_gemm_t(
    const float* __restrict__ feat, const float* __restrict__ B,
    const float* __restrict__ bias, float* __restrict__ outp, int N) {
    __shared__ float As[32 * AS_LD];   // [k][m], k-chunk 32, pad 132 -> 2-way reads (free)
    __shared__ float Bs[32 * TN];      // [k][c]
    int tid = threadIdx.x;
    int tx = tid & 15, ty = tid >> 4;
    int m0 = blockIdx.x * 128;
    float acc[8][TTN];
    #pragma unroll
    for (int r = 0; r < 8; ++r)
        #pragma unroll
        for (int c = 0; c < TTN; ++c) acc[r][c] = 0.f;

    for (int kc = 0; kc < 128; kc += 32) {
        // stage A: 128 nodes x 32 k (float4 global reads along k, b32 LDS scatter)
        for (int i = tid; i < 1024; i += 256) {
            int m = i >> 3, kq = (i & 7) << 2;
            int node = m0 + m;
            float4 f;
            if (node < N) f = *(const float4*)&feat[(size_t)node * 128 + kc + kq];
            else          f = make_float4(0.f, 0.f, 0.f, 0.f);
            As[(kq + 0) * AS_LD + m] = f.x;
            As[(kq + 1) * AS_LD + m] = f.y;
            As[(kq + 2) * AS_LD + m] = f.z;
            As[(kq + 3) * AS_LD + m] = f.w;
        }
        // stage B: 32 k x TN cols
        for (int i = tid; i < 8 * TN; i += 256) {
            int k = i / (TN / 4), cq = (i % (TN / 4)) << 2;
            *(float4*)&Bs[k * TN + cq] = *(const float4*)&B[(size_t)(kc + k) * TN + cq];
        }
        __syncthreads();
        #pragma unroll 8
        for (int kk = 0; kk < 32; ++kk) {
            const float* ar = &As[kk * AS_LD];
            float4 a0 = *(const float4*)(ar + 4 * tx);
            float4 a1 = *(const float4*)(ar + 64 + 4 * tx);
            const float* br = &Bs[kk * TN + TTN * ty];
            float4 b0v = *(const float4*)br;
            float a[8] = {a0.x, a0.y, a0.z, a0.w, a1.x, a1.y, a1.z, a1.w};
            float b[TTN];
            b[0] = b0v.x; b[1] = b0v.y; b[2] = b0v.z; b[3] = b0v.w;
            if (TTN == 8) {
                float4 b1v = *(const float4*)(br + 4);
                b[4] = b1v.x; b[5] = b1v.y; b[6] = b1v.z; b[7] = b1v.w;
            }
            #pragma unroll
            for (int r = 0; r < 8; ++r)
                #pragma unroll
                for (int c = 0; c < TTN; ++c) acc[r][c] += a[r] * b[c];
        }
        __syncthreads();
    }
    // epilogue
    float bb[TTN];
    #pragma unroll
    for (int c = 0; c < TTN; ++c) bb[c] = RELU ? bias[TTN * ty + c] : 0.f;
    #pragma unroll
    for (int r = 0; r < 8; ++r) {
        int node = m0 + ((r < 4) ? (4 * tx + r) : (64 + 4 * tx + (r - 4)));
        if (node >= N) continue;
        #pragma unroll
        for (int g = 0; g < TTN / 4; ++g) {
            float4 o;
            o.x = acc[r][g * 4 + 0] + bb[g * 4 + 0];
            o.y = acc[r][g * 4 + 1] + bb[g * 4 + 1];
            o.z = acc[r][g * 4 + 2] + bb[g * 4 + 2];
            o.w = acc[r][g * 4 + 3] + bb[g * 4 + 3];
            if (RELU) {
                o.x = fmaxf(o.x, 0.f); o.y = fmaxf(o.y, 0.f);
                o.z = fmaxf(o.z, 0.f); o.w = fmaxf(o.w, 0.f);
            }
            *(float4*)&outp[(size_t)node * TN + TTN * ty + g * 4] = o;
        }
    }
}

// ---------- K5: per-node reductions: a_self, a_neigh, gpart, fdotg ----------
__global__ __launch_bounds__(256) void k_node_red(
    const float* __restrict__ feat, const float* __restrict__ h0, const float* __restrict__ h1,
    const float* __restrict__ att, const float* __restrict__ Wg,
    float* __restrict__ a_self, float* __restrict__ a_neigh,
    float* __restrict__ gpart, float* __restrict__ fdotg, int N) {
    int r = blockIdx.x * 4 + (threadIdx.x >> 6);
    int lane = threadIdx.x & 63;
    if (r >= N) return;
    float2 f  = ((const float2*)(feat + (size_t)r * 128))[lane];
    float2 x0 = ((const float2*)(h0 + (size_t)r * 128))[lane];
    float2 x1 = ((const float2*)(h1 + (size_t)r * 128))[lane];
    float2 A0 = ((const float2*)att)[lane];
    float2 A1 = ((const float2*)(att + 128))[lane];
    float2 G  = ((const float2*)Wg)[lane];          // Wg[0:128]   (self feat)
    float2 G2 = ((const float2*)(Wg + 192))[lane];  // Wg[192:320] (neigh mean)
    float s0 = x0.x * A0.x + x0.y * A0.y;
    float s1 = x1.x * A1.x + x1.y * A1.y;
    float s2 = f.x * G.x + f.y * G.y;
    float s3 = f.x * G2.x + f.y * G2.y;
    #pragma unroll
    for (int off = 32; off; off >>= 1) {
        s0 += __shfl_xor(s0, off, 64);
        s1 += __shfl_xor(s1, off, 64);
        s2 += __shfl_xor(s2, off, 64);
        s3 += __shfl_xor(s3, off, 64);
    }
    if (lane == 0) {
        a_self[r]  = (s0 >= 0.f) ? s0 : 0.2f * s0;
        a_neigh[r] = (s1 >= 0.f) ? s1 : 0.2f * s1;
        gpart[r]   = s2;
        fdotg[r]   = s3;
    }
}

// ---------- K6: per-row CSR aggregation + gate + dual batch-norm + sum ----------
__global__ __launch_bounds__(256) void k_aggregate(
    const int* __restrict__ cols, const float* __restrict__ vals,
    const int* __restrict__ rowptr, const int* __restrict__ edge_idx,
    const float* __restrict__ h0, const float* __restrict__ h1, const float* __restrict__ zj,
    const float* __restrict__ a_self, const float* __restrict__ a_neigh,
    const float* __restrict__ gpart, const float* __restrict__ fdotg,
    const float* __restrict__ Wg,
    const float* __restrict__ scale0, const float* __restrict__ offset0,
    const float* __restrict__ scale1, const float* __restrict__ offset1,
    float* __restrict__ out, int N) {
    int r = blockIdx.x * 4 + (threadIdx.x >> 6);
    int lane = threadIdx.x & 63;
    if (r >= N) return;
    int jb = rowptr[r], je = rowptr[r + 1];
    float2 acca = {0.f, 0.f};
    float zmax = -__builtin_inff();
    float asr = a_self[r];
    // vector loop: one edge per iteration, whole wave gathers h1/zj rows
    int c_next = 0; float an_next = 0.f;
    if (jb < je) { int e = edge_idx[jb]; c_next = cols[e]; an_next = a_neigh[c_next]; }
    for (int j = jb; j < je; ++j) {
        int c = c_next; float an = an_next;
        if (j + 1 < je) {  // prefetch next edge's scalar chain
            int e2 = edge_idx[j + 1];
            c_next = cols[e2];
            an_next = a_neigh[c_next];
        }
        float es = asr + an;
        float2 h = ((const float2*)(h1 + (size_t)c * 128))[lane];
        float z = zj[(size_t)c * 64 + lane];
        acca.x += es * h.x; acca.y += es * h.y;
        zmax = fmaxf(zmax, z);
    }
    if (jb == je) zmax = 0.f;  // empty segment: -inf -> 0
    // scalar gate sum, lane-parallel over edges: sum v_e * fdotg[c_e]
    float gs_lin = 0.f;
    for (int j = jb + lane; j < je; j += 64) {
        int e = edge_idx[j];
        gs_lin += vals[e] * fdotg[cols[e]];
    }
    float gs = zmax * Wg[128 + lane] + gs_lin;
    #pragma unroll
    for (int off = 32; off; off >>= 1) gs += __shfl_xor(gs, off, 64);
    float gate = gpart[r] + gs;
    float2 ag = {acca.x * gate, acca.y * gate};
    // BN on h0 row
    float2 x0 = ((const float2*)(h0 + (size_t)r * 128))[lane];
    float m0s = x0.x + x0.y;
    #pragma unroll
    for (int off = 32; off; off >>= 1) m0s += __shfl_xor(m0s, off, 64);
    float m0 = m0s * (1.f / 128.f);
    float d0x = x0.x - m0, d0y = x0.y - m0;
    float v0s = d0x * d0x + d0y * d0y;
    #pragma unroll
    for (int off = 32; off; off >>= 1) v0s += __shfl_xor(v0s, off, 64);
    float inv0 = rsqrtf(v0s * (1.f / 128.f) + 1e-9f);
    // BN on gated aggregation
    float m1s = ag.x + ag.y;
    #pragma unroll
    for (int off = 32; off; off >>= 1) m1s += __shfl_xor(m1s, off, 64);
    float m1 = m1s * (1.f / 128.f);
    float d1x = ag.x - m1, d1y = ag.y - m1;
    float v1s = d1x * d1x + d1y * d1y;
    #pragma unroll
    for (int off = 32; off; off >>= 1) v1s += __shfl_xor(v1s, off, 64);
    float inv1 = rsqrtf(v1s * (1.f / 128.f) + 1e-9f);
    float2 sc0 = ((const float2*)scale0)[lane], of0 = ((const float2*)offset0)[lane];
    float2 sc1 = ((const float2*)scale1)[lane], of1 = ((const float2*)offset1)[lane];
    float2 o;
    o.x = d0x * sc0.x * inv0 + of0.x + d1x * sc1.x * inv1 + of1.x;
    o.y = d0y * sc0.y * inv0 + of0.y + d1y * sc1.y * inv1 + of1.y;
    ((float2*)(out + (size_t)r * 128))[lane] = o;
}

extern "C" void kernel_launch(void* const* d_in, const int* in_sizes, int n_in,
                              void* d_out, int out_size, void* d_ws, size_t ws_size,
                              hipStream_t stream) {
    const int*   rows   = (const int*)d_in[0];
    const int*   cols   = (const int*)d_in[1];
    const float* vals   = (const float*)d_in[2];
    const float* feat   = (const float*)d_in[3];
    const float* W0     = (const float*)d_in[4];
    const float* b0     = (const float*)d_in[5];
    const float* W1     = (const float*)d_in[6];
    const float* b1     = (const float*)d_in[7];
    const float* att    = (const float*)d_in[8];
    const float* Wp     = (const float*)d_in[9];
    const float* Wg     = (const float*)d_in[10];
    const float* offset0 = (const float*)d_in[11];
    const float* scale0  = (const float*)d_in[12];
    const float* offset1 = (const float*)d_in[13];
    const float* scale1  = (const float*)d_in[14];
    float* out = (float*)d_out;

    const int E = in_sizes[0];
    const int N = in_sizes[3] / DIN;

    char* ws = (char*)d_ws;
    float* h0      = (float*)ws; ws += (size_t)N * 128 * sizeof(float);
    float* h1      = (float*)ws; ws += (size_t)N * 128 * sizeof(float);
    float* zj      = (float*)ws; ws += (size_t)N * 64 * sizeof(float);
    float* a_self  = (float*)ws; ws += (size_t)N * sizeof(float);
    float* a_neigh = (float*)ws; ws += (size_t)N * sizeof(float);
    float* gpart   = (float*)ws; ws += (size_t)N * sizeof(float);
    float* fdotg   = (float*)ws; ws += (size_t)N * sizeof(float);
    int* deg      = (int*)ws; ws += (size_t)(N + 1) * sizeof(int);
    int* rowptr   = (int*)ws; ws += (size_t)(N + 1) * sizeof(int);
    int* bsum     = (int*)ws; ws += 64 * sizeof(int);
    int* boff     = (int*)ws; ws += 64 * sizeof(int);
    int* slot     = (int*)ws; ws += (size_t)E * sizeof(int);
    int* edge_idx = (int*)ws; ws += (size_t)E * sizeof(int);

    hipMemsetAsync(deg, 0, (size_t)(N + 1) * sizeof(int), stream);

    k_deg<<<(E + 255) / 256, 256, 0, stream>>>(rows, deg, slot, E);
    int nb = (N + 1023) >> 10;  // 49 for N=50000; k_scan2 requires nb <= 64
    k_scan1<<<nb, 1024, 0, stream>>>(deg, rowptr, bsum, N);
    k_scan2<<<1, 64, 0, stream>>>(bsum, boff, rowptr, nb, N);
    k_scan3<<<(N + 255) / 256, 256, 0, stream>>>(rowptr, boff, N);
    k_scatter<<<(E + 255) / 256, 256, 0, stream>>>(rows, rowptr, slot, edge_idx, E);

    int mt = (N + 127) / 128;
    k_gemm_t<128, 8, true ><<<mt, 256, 0, stream>>>(feat, W0, b0, h0, N);
    k_gemm_t<128, 8, true ><<<mt, 256, 0, stream>>>(feat, W1, b1, h1, N);
    k_gemm_t< 64, 4, false><<<mt, 256, 0, stream>>>(feat, Wp, nullptr, zj, N);

    int nb4 = (N + 3) / 4;
    k_node_red<<<nb4, 256, 0, stream>>>(feat, h0, h1, att, Wg, a_self, a_neigh, gpart, fdotg, N);
    k_aggregate<<<nb4, 256, 0, stream>>>(cols, vals, rowptr, edge_idx, h0, h1, zj,
                                         a_self, a_neigh, gpart, fdotg, Wg,
                                         scale0, offset0, scale1, offset1, out, N);
}

// Round 4
// 342.538 us; speedup vs baseline: 1.3735x; 1.1116x over previous
//
#include <hip/hip_runtime.h>

#define DIN 128
#define DG 64

// ---- bf16 helpers (RNE) ----
static __device__ __forceinline__ unsigned short f2bf(float x) {
    unsigned u = __builtin_bit_cast(unsigned, x);
    u = (u + 0x7FFF + ((u >> 16) & 1)) >> 16;
    return (unsigned short)u;
}
static __device__ __forceinline__ float bf2f(unsigned short s) {
    return __builtin_bit_cast(float, (unsigned)s << 16);
}

// ---------- K1: per-row degree + slot capture ----------
__global__ void k_deg(const int* __restrict__ rows, int* __restrict__ deg,
                      int* __restrict__ slot, int E) {
    int e = blockIdx.x * blockDim.x + threadIdx.x;
    if (e < E) slot[e] = atomicAdd(&deg[rows[e]], 1);
}

// ---------- K2a: per-block exclusive scan (1024 elems/block) ----------
__global__ __launch_bounds__(1024) void k_scan1(const int* __restrict__ deg,
                                                int* __restrict__ rowptr,
                                                int* __restrict__ bsum, int n) {
    __shared__ int wsum[16];
    __shared__ int woff[16];
    int tid = threadIdx.x;
    int lane = tid & 63, w = tid >> 6;
    int i = blockIdx.x * 1024 + tid;
    int v = (i < n) ? deg[i] : 0;
    int x = v;
    #pragma unroll
    for (int off = 1; off < 64; off <<= 1) {
        int y = __shfl_up(x, off, 64);
        if (lane >= off) x += y;
    }
    if (lane == 63) wsum[w] = x;
    __syncthreads();
    if (w == 0) {
        int t = (lane < 16) ? wsum[lane] : 0;
        int xx = t;
        #pragma unroll
        for (int off = 1; off < 16; off <<= 1) {
            int y = __shfl_up(xx, off, 64);
            if (lane >= off) xx += y;
        }
        if (lane < 16) woff[lane] = xx - t;  // exclusive
    }
    __syncthreads();
    if (i < n) rowptr[i] = x - v + woff[w];
    if (tid == 1023) bsum[blockIdx.x] = woff[15] + wsum[15];
}

// ---------- K2b: scan of block sums (single wave, nb<=64) ----------
__global__ void k_scan2(const int* __restrict__ bsum, int* __restrict__ boff,
                        int* __restrict__ rowptr, int nb, int n) {
    int lane = threadIdx.x;
    int v = (lane < nb) ? bsum[lane] : 0;
    int x = v;
    #pragma unroll
    for (int off = 1; off < 64; off <<= 1) {
        int y = __shfl_up(x, off, 64);
        if (lane >= off) x += y;
    }
    boff[lane] = x - v;
    if (lane == 63) rowptr[n] = x;  // grand total
}

// ---------- K2c: add block offsets ----------
__global__ void k_scan3(int* __restrict__ rowptr, const int* __restrict__ boff, int n) {
    int i = blockIdx.x * blockDim.x + threadIdx.x;
    if (i < n) rowptr[i] += boff[i >> 10];
}

// ---------- K3: scatter edge ids into CSR order ----------
__global__ void k_scatter(const int* __restrict__ rows, const int* __restrict__ rowptr,
                          const int* __restrict__ slot, int* __restrict__ edge_idx, int E) {
    int e = blockIdx.x * blockDim.x + threadIdx.x;
    if (e < E) edge_idx[rowptr[rows[e]] + slot[e]] = e;
}

// ---------- K4: fused triple GEMM ----------
// block tile 128 nodes x TN cols, thread tile 8 x TTN
// mode 0: f32 + relu -> h0[node*128 + c]
// mode 1: bf16 + relu -> hb[node*128 + c]   (h1, gather-compressed; gate path unaffected)
// mode 2: f32        -> zj[node*64 + c]     (MUST stay f32: feeds gate sign, bn(c*x)=sign(c)*bn(x))
#define AS_LD 132
template<int TN, int TTN, int MODE>
static __device__ __forceinline__ void gemm_body(
    const float* __restrict__ feat, const float* __restrict__ B,
    const float* __restrict__ bias, float* __restrict__ h0,
    unsigned short* __restrict__ hb, float* __restrict__ zj,
    int N, float* As, float* Bs) {
    int tid = threadIdx.x;
    int tx = tid & 15, ty = tid >> 4;
    int m0 = blockIdx.x * 128;
    float acc[8][TTN];
    #pragma unroll
    for (int r = 0; r < 8; ++r)
        #pragma unroll
        for (int c = 0; c < TTN; ++c) acc[r][c] = 0.f;

    for (int kc = 0; kc < 128; kc += 32) {
        for (int i = tid; i < 1024; i += 256) {
            int m = i >> 3, kq = (i & 7) << 2;
            int node = m0 + m;
            float4 f;
            if (node < N) f = *(const float4*)&feat[(size_t)node * 128 + kc + kq];
            else          f = make_float4(0.f, 0.f, 0.f, 0.f);
            As[(kq + 0) * AS_LD + m] = f.x;
            As[(kq + 1) * AS_LD + m] = f.y;
            As[(kq + 2) * AS_LD + m] = f.z;
            As[(kq + 3) * AS_LD + m] = f.w;
        }
        for (int i = tid; i < 8 * TN; i += 256) {
            int k = i / (TN / 4), cq = (i % (TN / 4)) << 2;
            *(float4*)&Bs[k * TN + cq] = *(const float4*)&B[(size_t)(kc + k) * TN + cq];
        }
        __syncthreads();
        #pragma unroll 8
        for (int kk = 0; kk < 32; ++kk) {
            const float* ar = &As[kk * AS_LD];
            float4 a0 = *(const float4*)(ar + 4 * tx);
            float4 a1 = *(const float4*)(ar + 64 + 4 * tx);
            const float* br = &Bs[kk * TN + TTN * ty];
            float4 b0v = *(const float4*)br;
            float a[8] = {a0.x, a0.y, a0.z, a0.w, a1.x, a1.y, a1.z, a1.w};
            float b[TTN];
            b[0] = b0v.x; b[1] = b0v.y; b[2] = b0v.z; b[3] = b0v.w;
            if (TTN == 8) {
                float4 b1v = *(const float4*)(br + 4);
                b[4] = b1v.x; b[5] = b1v.y; b[6] = b1v.z; b[7] = b1v.w;
            }
            #pragma unroll
            for (int r = 0; r < 8; ++r)
                #pragma unroll
                for (int c = 0; c < TTN; ++c) acc[r][c] += a[r] * b[c];
        }
        __syncthreads();
    }
    float bb[TTN];
    #pragma unroll
    for (int c = 0; c < TTN; ++c) bb[c] = (MODE == 2) ? 0.f : bias[TTN * ty + c];
    #pragma unroll
    for (int r = 0; r < 8; ++r) {
        int node = m0 + ((r < 4) ? (4 * tx + r) : (64 + 4 * tx + (r - 4)));
        if (node >= N) continue;
        float v[TTN];
        #pragma unroll
        for (int c = 0; c < TTN; ++c) {
            v[c] = acc[r][c] + bb[c];
            if (MODE != 2) v[c] = fmaxf(v[c], 0.f);
        }
        if (MODE == 0) {
            #pragma unroll
            for (int g = 0; g < TTN / 4; ++g)
                *(float4*)&h0[(size_t)node * 128 + TTN * ty + g * 4] =
                    make_float4(v[g*4], v[g*4+1], v[g*4+2], v[g*4+3]);
        } else if (MODE == 1) {
            unsigned p[4];
            #pragma unroll
            for (int g = 0; g < 4; ++g)
                p[g] = (unsigned)f2bf(v[2*g]) | ((unsigned)f2bf(v[2*g+1]) << 16);
            *(uint4*)&hb[(size_t)node * 128 + 8 * ty] = make_uint4(p[0], p[1], p[2], p[3]);
        } else {
            *(float4*)&zj[(size_t)node * 64 + 4 * ty] =
                make_float4(v[0], v[1], v[2], v[3]);
        }
    }
}

__global__ __launch_bounds__(256) void k_gemm3(
    const float* __restrict__ feat,
    const float* __restrict__ W0, const float* __restrict__ b0,
    const float* __restrict__ W1, const float* __restrict__ b1,
    const float* __restrict__ Wp,
    float* __restrict__ h0, unsigned short* __restrict__ hb,
    float* __restrict__ zj, int N) {
    __shared__ float As[32 * AS_LD];
    __shared__ float Bs[32 * 128];
    int g = blockIdx.y;
    if (g == 0)      gemm_body<128, 8, 0>(feat, W0, b0, h0, hb, zj, N, As, Bs);
    else if (g == 1) gemm_body<128, 8, 1>(feat, W1, b1, h0, hb, zj, N, As, Bs);
    else             gemm_body< 64, 4, 2>(feat, Wp, nullptr, h0, hb, zj, N, As, Bs);
}

// ---------- K5: per-node reductions: a_self, a_neigh, gpart, fdotg ----------
__global__ __launch_bounds__(256) void k_node_red(
    const float* __restrict__ feat, const float* __restrict__ h0,
    const unsigned short* __restrict__ hb,
    const float* __restrict__ att, const float* __restrict__ Wg,
    float* __restrict__ a_self, float* __restrict__ a_neigh,
    float* __restrict__ gpart, float* __restrict__ fdotg, int N) {
    int r = blockIdx.x * 4 + (threadIdx.x >> 6);
    int lane = threadIdx.x & 63;
    if (r >= N) return;
    float2 f  = ((const float2*)(feat + (size_t)r * 128))[lane];
    float2 x0 = ((const float2*)(h0 + (size_t)r * 128))[lane];
    ushort2 h1v = ((const ushort2*)(hb + (size_t)r * 128))[lane];
    float2 A0 = ((const float2*)att)[lane];
    float2 A1 = ((const float2*)(att + 128))[lane];
    float2 G  = ((const float2*)Wg)[lane];          // Wg[0:128]   (self feat)
    float2 G2 = ((const float2*)(Wg + 192))[lane];  // Wg[192:320] (neigh mean)
    float s0 = x0.x * A0.x + x0.y * A0.y;
    float s1 = bf2f(h1v.x) * A1.x + bf2f(h1v.y) * A1.y;
    float s2 = f.x * G.x + f.y * G.y;
    float s3 = f.x * G2.x + f.y * G2.y;
    #pragma unroll
    for (int off = 32; off; off >>= 1) {
        s0 += __shfl_xor(s0, off, 64);
        s1 += __shfl_xor(s1, off, 64);
        s2 += __shfl_xor(s2, off, 64);
        s3 += __shfl_xor(s3, off, 64);
    }
    if (lane == 0) {
        a_self[r]  = (s0 >= 0.f) ? s0 : 0.2f * s0;
        a_neigh[r] = (s1 >= 0.f) ? s1 : 0.2f * s1;
        gpart[r]   = s2;
        fdotg[r]   = s3;
    }
}

// ---------- K6: per-row CSR aggregation + gate + dual batch-norm + sum ----------
__global__ __launch_bounds__(256) void k_aggregate(
    const int* __restrict__ cols, const float* __restrict__ vals,
    const int* __restrict__ rowptr, const int* __restrict__ edge_idx,
    const float* __restrict__ h0, const unsigned short* __restrict__ hb,
    const float* __restrict__ zj,
    const float* __restrict__ a_self, const float* __restrict__ a_neigh,
    const float* __restrict__ gpart, const float* __restrict__ fdotg,
    const float* __restrict__ Wg,
    const float* __restrict__ scale0, const float* __restrict__ offset0,
    const float* __restrict__ scale1, const float* __restrict__ offset1,
    float* __restrict__ out, int N) {
    int r = blockIdx.x * 4 + (threadIdx.x >> 6);
    int lane = threadIdx.x & 63;
    if (r >= N) return;
    int jb = rowptr[r], je = rowptr[r + 1];
    float2 acca = {0.f, 0.f};
    float zmax = -__builtin_inff();
    float asr = a_self[r];
    int c_next = 0; float an_next = 0.f;
    if (jb < je) { int e = edge_idx[jb]; c_next = cols[e]; an_next = a_neigh[c_next]; }
    for (int j = jb; j < je; ++j) {
        int c = c_next; float an = an_next;
        if (j + 1 < je) {
            int e2 = edge_idx[j + 1];
            c_next = cols[e2];
            an_next = a_neigh[c_next];
        }
        float es = asr + an;
        ushort2 hv = ((const ushort2*)(hb + (size_t)c * 128))[lane];
        float z = zj[(size_t)c * 64 + lane];
        acca.x += es * bf2f(hv.x); acca.y += es * bf2f(hv.y);
        zmax = fmaxf(zmax, z);
    }
    if (jb == je) zmax = 0.f;  // empty segment: -inf -> 0
    // scalar gate sum, lane-parallel over edges: sum v_e * fdotg[c_e]  (all f32)
    float gs_lin = 0.f;
    for (int j = jb + lane; j < je; j += 64) {
        int e = edge_idx[j];
        gs_lin += vals[e] * fdotg[cols[e]];
    }
    float gs = zmax * Wg[128 + lane] + gs_lin;
    #pragma unroll
    for (int off = 32; off; off >>= 1) gs += __shfl_xor(gs, off, 64);
    float gate = gpart[r] + gs;
    float2 ag = {acca.x * gate, acca.y * gate};
    // BN on h0 row
    float2 x0 = ((const float2*)(h0 + (size_t)r * 128))[lane];
    float m0s = x0.x + x0.y;
    #pragma unroll
    for (int off = 32; off; off >>= 1) m0s += __shfl_xor(m0s, off, 64);
    float m0 = m0s * (1.f / 128.f);
    float d0x = x0.x - m0, d0y = x0.y - m0;
    float v0s = d0x * d0x + d0y * d0y;
    #pragma unroll
    for (int off = 32; off; off >>= 1) v0s += __shfl_xor(v0s, off, 64);
    float inv0 = rsqrtf(v0s * (1.f / 128.f) + 1e-9f);
    // BN on gated aggregation
    float m1s = ag.x + ag.y;
    #pragma unroll
    for (int off = 32; off; off >>= 1) m1s += __shfl_xor(m1s, off, 64);
    float m1 = m1s * (1.f / 128.f);
    float d1x = ag.x - m1, d1y = ag.y - m1;
    float v1s = d1x * d1x + d1y * d1y;
    #pragma unroll
    for (int off = 32; off; off >>= 1) v1s += __shfl_xor(v1s, off, 64);
    float inv1 = rsqrtf(v1s * (1.f / 128.f) + 1e-9f);
    float2 sc0 = ((const float2*)scale0)[lane], of0 = ((const float2*)offset0)[lane];
    float2 sc1 = ((const float2*)scale1)[lane], of1 = ((const float2*)offset1)[lane];
    float2 o;
    o.x = d0x * sc0.x * inv0 + of0.x + d1x * sc1.x * inv1 + of1.x;
    o.y = d0y * sc0.y * inv0 + of0.y + d1y * sc1.y * inv1 + of1.y;
    ((float2*)(out + (size_t)r * 128))[lane] = o;
}

extern "C" void kernel_launch(void* const* d_in, const int* in_sizes, int n_in,
                              void* d_out, int out_size, void* d_ws, size_t ws_size,
                              hipStream_t stream) {
    const int*   rows   = (const int*)d_in[0];
    const int*   cols   = (const int*)d_in[1];
    const float* vals   = (const float*)d_in[2];
    const float* feat   = (const float*)d_in[3];
    const float* W0     = (const float*)d_in[4];
    const float* b0     = (const float*)d_in[5];
    const float* W1     = (const float*)d_in[6];
    const float* b1     = (const float*)d_in[7];
    const float* att    = (const float*)d_in[8];
    const float* Wp     = (const float*)d_in[9];
    const float* Wg     = (const float*)d_in[10];
    const float* offset0 = (const float*)d_in[11];
    const float* scale0  = (const float*)d_in[12];
    const float* offset1 = (const float*)d_in[13];
    const float* scale1  = (const float*)d_in[14];
    float* out = (float*)d_out;

    const int E = in_sizes[0];
    const int N = in_sizes[3] / DIN;

    char* ws = (char*)d_ws;
    float* h0          = (float*)ws;          ws += (size_t)N * 128 * sizeof(float);
    unsigned short* hb = (unsigned short*)ws; ws += (size_t)N * 128 * sizeof(unsigned short);
    float* zj          = (float*)ws;          ws += (size_t)N * 64 * sizeof(float);
    float* a_self  = (float*)ws; ws += (size_t)N * sizeof(float);
    float* a_neigh = (float*)ws; ws += (size_t)N * sizeof(float);
    float* gpart   = (float*)ws; ws += (size_t)N * sizeof(float);
    float* fdotg   = (float*)ws; ws += (size_t)N * sizeof(float);
    int* deg      = (int*)ws; ws += (size_t)(N + 1) * sizeof(int);
    int* rowptr   = (int*)ws; ws += (size_t)(N + 1) * sizeof(int);
    int* bsum     = (int*)ws; ws += 64 * sizeof(int);
    int* boff     = (int*)ws; ws += 64 * sizeof(int);
    int* slot     = (int*)ws; ws += (size_t)E * sizeof(int);
    int* edge_idx = (int*)ws; ws += (size_t)E * sizeof(int);

    hipMemsetAsync(deg, 0, (size_t)(N + 1) * sizeof(int), stream);

    k_deg<<<(E + 255) / 256, 256, 0, stream>>>(rows, deg, slot, E);
    int nb = (N + 1023) >> 10;  // 49 for N=50000; k_scan2 requires nb <= 64
    k_scan1<<<nb, 1024, 0, stream>>>(deg, rowptr, bsum, N);
    k_scan2<<<1, 64, 0, stream>>>(bsum, boff, rowptr, nb, N);
    k_scan3<<<(N + 255) / 256, 256, 0, stream>>>(rowptr, boff, N);
    k_scatter<<<(E + 255) / 256, 256, 0, stream>>>(rows, rowptr, slot, edge_idx, E);

    int mt = (N + 127) / 128;
    dim3 gg(mt, 3);
    k_gemm3<<<gg, 256, 0, stream>>>(feat, W0, b0, W1, b1, Wp, h0, hb, zj, N);

    int nb4 = (N + 3) / 4;
    k_node_red<<<nb4, 256, 0, stream>>>(feat, h0, hb, att, Wg, a_self, a_neigh, gpart, fdotg, N);
    k_aggregate<<<nb4, 256, 0, stream>>>(cols, vals, rowptr, edge_idx, h0, hb, zj,
                                         a_self, a_neigh, gpart, fdotg, Wg,
                                         scale0, offset0, scale1, offset1, out, N);
}

// Round 5
// 278.162 us; speedup vs baseline: 1.6914x; 1.2314x over previous
//
#include <hip/hip_runtime.h>

#define DIN 128
#define DG 64

// ---- bf16 helpers (RNE) ----
static __device__ __forceinline__ unsigned short f2bf(float x) {
    unsigned u = __builtin_bit_cast(unsigned, x);
    u = (u + 0x7FFF + ((u >> 16) & 1)) >> 16;
    return (unsigned short)u;
}
static __device__ __forceinline__ float bf2f(unsigned short s) {
    return __builtin_bit_cast(float, (unsigned)s << 16);
}

// ---------- K1: per-row degree + slot capture ----------
__global__ void k_deg(const int* __restrict__ rows, int* __restrict__ deg,
                      int* __restrict__ slot, int E) {
    int e = blockIdx.x * blockDim.x + threadIdx.x;
    if (e < E) slot[e] = atomicAdd(&deg[rows[e]], 1);
}

// ---------- K2a: per-block exclusive scan (1024 elems/block) ----------
__global__ __launch_bounds__(1024) void k_scan1(const int* __restrict__ deg,
                                                int* __restrict__ rowptr,
                                                int* __restrict__ bsum, int n) {
    __shared__ int wsum[16];
    __shared__ int woff[16];
    int tid = threadIdx.x;
    int lane = tid & 63, w = tid >> 6;
    int i = blockIdx.x * 1024 + tid;
    int v = (i < n) ? deg[i] : 0;
    int x = v;
    #pragma unroll
    for (int off = 1; off < 64; off <<= 1) {
        int y = __shfl_up(x, off, 64);
        if (lane >= off) x += y;
    }
    if (lane == 63) wsum[w] = x;
    __syncthreads();
    if (w == 0) {
        int t = (lane < 16) ? wsum[lane] : 0;
        int xx = t;
        #pragma unroll
        for (int off = 1; off < 16; off <<= 1) {
            int y = __shfl_up(xx, off, 64);
            if (lane >= off) xx += y;
        }
        if (lane < 16) woff[lane] = xx - t;  // exclusive
    }
    __syncthreads();
    if (i < n) rowptr[i] = x - v + woff[w];
    if (tid == 1023) bsum[blockIdx.x] = woff[15] + wsum[15];
}

// ---------- K2b: scan of block sums (single wave, nb<=64) ----------
__global__ void k_scan2(const int* __restrict__ bsum, int* __restrict__ boff,
                        int* __restrict__ rowptr, int nb, int n) {
    int lane = threadIdx.x;
    int v = (lane < nb) ? bsum[lane] : 0;
    int x = v;
    #pragma unroll
    for (int off = 1; off < 64; off <<= 1) {
        int y = __shfl_up(x, off, 64);
        if (lane >= off) x += y;
    }
    boff[lane] = x - v;
    if (lane == 63) rowptr[n] = x;  // grand total
}

// ---------- K2c: add block offsets ----------
__global__ void k_scan3(int* __restrict__ rowptr, const int* __restrict__ boff, int n) {
    int i = blockIdx.x * blockDim.x + threadIdx.x;
    if (i < n) rowptr[i] += boff[i >> 10];
}

// ---------- K3: scatter {col, val} into CSR slot ----------
__global__ void k_scatter(const int* __restrict__ rows, const int* __restrict__ cols,
                          const float* __restrict__ vals,
                          const int* __restrict__ rowptr, const int* __restrict__ slot,
                          int2* __restrict__ cv, int E) {
    int e = blockIdx.x * blockDim.x + threadIdx.x;
    if (e < E) {
        int dst = rowptr[rows[e]] + slot[e];
        cv[dst] = make_int2(cols[e], __builtin_bit_cast(int, vals[e]));
    }
}

// ---------- K3b: finalize edge meta: {c_bits, a_neigh[c], val*fdotg[c], 0} ----------
__global__ void k_edgemeta(const int2* __restrict__ cv,
                           const float* __restrict__ a_neigh,
                           const float* __restrict__ fdotg,
                           float4* __restrict__ meta, int E) {
    int j = blockIdx.x * blockDim.x + threadIdx.x;
    if (j < E) {
        int2 p = cv[j];
        int c = p.x;
        float val = __builtin_bit_cast(float, p.y);
        meta[j] = make_float4(__builtin_bit_cast(float, c),
                              a_neigh[c], val * fdotg[c], 0.f);
    }
}

// ---------- K4: fused triple GEMM + per-node dots ----------
// mode 0: f32 + relu -> h0; also a_self (LDS-reduce), gpart/fdotg (k-loop dots)
// mode 1: bf16 + relu -> hb; also a_neigh (LDS-reduce)
// mode 2: f32        -> zj   (f32 REQUIRED: feeds gate sign, bn(c*x)=sign(c)*bn(x))
#define AS_LD 132
template<int TN, int TTN, int MODE>
static __device__ __forceinline__ void gemm_body(
    const float* __restrict__ feat, const float* __restrict__ B,
    const float* __restrict__ bias,
    const float* __restrict__ att, const float* __restrict__ Wg,
    float* __restrict__ h0, unsigned short* __restrict__ hb, float* __restrict__ zj,
    float* __restrict__ a_self, float* __restrict__ a_neigh,
    float* __restrict__ gpart, float* __restrict__ fdotg,
    int N, float* As, float* Bs) {
    int tid = threadIdx.x;
    int tx = tid & 15, ty = tid >> 4;
    int m0 = blockIdx.x * 128;
    float acc[8][TTN];
    #pragma unroll
    for (int r = 0; r < 8; ++r)
        #pragma unroll
        for (int c = 0; c < TTN; ++c) acc[r][c] = 0.f;
    float gdot[8], fdot[8];
    #pragma unroll
    for (int r = 0; r < 8; ++r) { gdot[r] = 0.f; fdot[r] = 0.f; }

    for (int kc = 0; kc < 128; kc += 32) {
        for (int i = tid; i < 1024; i += 256) {
            int m = i >> 3, kq = (i & 7) << 2;
            int node = m0 + m;
            float4 f;
            if (node < N) f = *(const float4*)&feat[(size_t)node * 128 + kc + kq];
            else          f = make_float4(0.f, 0.f, 0.f, 0.f);
            As[(kq + 0) * AS_LD + m] = f.x;
            As[(kq + 1) * AS_LD + m] = f.y;
            As[(kq + 2) * AS_LD + m] = f.z;
            As[(kq + 3) * AS_LD + m] = f.w;
        }
        for (int i = tid; i < 8 * TN; i += 256) {
            int k = i / (TN / 4), cq = (i % (TN / 4)) << 2;
            *(float4*)&Bs[k * TN + cq] = *(const float4*)&B[(size_t)(kc + k) * TN + cq];
        }
        __syncthreads();
        #pragma unroll 8
        for (int kk = 0; kk < 32; ++kk) {
            const float* ar = &As[kk * AS_LD];
            float4 a0 = *(const float4*)(ar + 4 * tx);
            float4 a1 = *(const float4*)(ar + 64 + 4 * tx);
            const float* br = &Bs[kk * TN + TTN * ty];
            float4 b0v = *(const float4*)br;
            float a[8] = {a0.x, a0.y, a0.z, a0.w, a1.x, a1.y, a1.z, a1.w};
            float b[TTN];
            b[0] = b0v.x; b[1] = b0v.y; b[2] = b0v.z; b[3] = b0v.w;
            if (TTN == 8) {
                float4 b1v = *(const float4*)(br + 4);
                b[4] = b1v.x; b[5] = b1v.y; b[6] = b1v.z; b[7] = b1v.w;
            }
            #pragma unroll
            for (int r = 0; r < 8; ++r)
                #pragma unroll
                for (int c = 0; c < TTN; ++c) acc[r][c] += a[r] * b[c];
            if (MODE == 0) {  // gate dots on feat (uniform scalar weights)
                float g1 = Wg[kc + kk];        // Wg[0:128]   -> gpart
                float g2 = Wg[192 + kc + kk];  // Wg[192:320] -> fdotg
                #pragma unroll
                for (int r = 0; r < 8; ++r) {
                    gdot[r] += a[r] * g1;
                    fdot[r] += a[r] * g2;
                }
            }
        }
        __syncthreads();
    }
    float bb[TTN];
    #pragma unroll
    for (int c = 0; c < TTN; ++c) bb[c] = (MODE == 2) ? 0.f : bias[TTN * ty + c];
    float attv[TTN];
    if (MODE <= 1) {
        #pragma unroll
        for (int c = 0; c < TTN; ++c) attv[c] = att[(MODE == 0 ? 0 : 128) + TTN * ty + c];
    }
    float* red = Bs;  // reuse: 16 ty x 128 rows (8 KB <= 16 KB)
    #pragma unroll
    for (int r = 0; r < 8; ++r) {
        int ridx = (r < 4) ? (4 * tx + r) : (64 + 4 * tx + (r - 4));
        int node = m0 + ridx;
        float v[TTN];
        #pragma unroll
        for (int c = 0; c < TTN; ++c) {
            v[c] = acc[r][c] + bb[c];
            if (MODE != 2) v[c] = fmaxf(v[c], 0.f);
        }
        if (MODE <= 1) {
            float pa = 0.f;
            #pragma unroll
            for (int c = 0; c < TTN; ++c) pa += v[c] * attv[c];
            red[ty * 128 + ridx] = pa;
        }
        if (node < N) {
            if (MODE == 0) {
                #pragma unroll
                for (int g = 0; g < TTN / 4; ++g)
                    *(float4*)&h0[(size_t)node * 128 + TTN * ty + g * 4] =
                        make_float4(v[g*4], v[g*4+1], v[g*4+2], v[g*4+3]);
            } else if (MODE == 1) {
                unsigned p[4];
                #pragma unroll
                for (int g = 0; g < 4; ++g)
                    p[g] = (unsigned)f2bf(v[2*g]) | ((unsigned)f2bf(v[2*g+1]) << 16);
                *(uint4*)&hb[(size_t)node * 128 + 8 * ty] = make_uint4(p[0], p[1], p[2], p[3]);
            } else {
                *(float4*)&zj[(size_t)node * 64 + 4 * ty] =
                    make_float4(v[0], v[1], v[2], v[3]);
            }
        }
    }
    if (MODE == 0 && ty == 0) {
        #pragma unroll
        for (int r = 0; r < 8; ++r) {
            int ridx = (r < 4) ? (4 * tx + r) : (64 + 4 * tx + (r - 4));
            int node = m0 + ridx;
            if (node < N) { gpart[node] = gdot[r]; fdotg[node] = fdot[r]; }
        }
    }
    if (MODE <= 1) {
        __syncthreads();
        if (tid < 128) {
            float s = 0.f;
            #pragma unroll
            for (int t = 0; t < 16; ++t) s += red[t * 128 + tid];
            int node = m0 + tid;
            if (node < N) {
                float av = (s >= 0.f) ? s : 0.2f * s;
                if (MODE == 0) a_self[node] = av;
                else           a_neigh[node] = av;
            }
        }
    }
}

__global__ __launch_bounds__(256) void k_gemm3(
    const float* __restrict__ feat,
    const float* __restrict__ W0, const float* __restrict__ b0,
    const float* __restrict__ W1, const float* __restrict__ b1,
    const float* __restrict__ Wp,
    const float* __restrict__ att, const float* __restrict__ Wg,
    float* __restrict__ h0, unsigned short* __restrict__ hb, float* __restrict__ zj,
    float* __restrict__ a_self, float* __restrict__ a_neigh,
    float* __restrict__ gpart, float* __restrict__ fdotg, int N) {
    __shared__ float As[32 * AS_LD];
    __shared__ float Bs[32 * 128];
    int g = blockIdx.y;
    if (g == 0)      gemm_body<128, 8, 0>(feat, W0, b0, att, Wg, h0, hb, zj, a_self, a_neigh, gpart, fdotg, N, As, Bs);
    else if (g == 1) gemm_body<128, 8, 1>(feat, W1, b1, att, Wg, h0, hb, zj, a_self, a_neigh, gpart, fdotg, N, As, Bs);
    else             gemm_body< 64, 4, 2>(feat, Wp, nullptr, att, Wg, h0, hb, zj, a_self, a_neigh, gpart, fdotg, N, As, Bs);
}

// ---------- K6: per-row CSR aggregation, chunked gathers for MLP ----------
template<int C>
static __device__ __forceinline__ void agg_chunk(
    const float4* __restrict__ meta, int j, int lane, float asr,
    const unsigned short* __restrict__ hb, const float* __restrict__ zj,
    float2& acca, float& zmax, float& vfsum) {
    float4 m[C];
    #pragma unroll
    for (int t = 0; t < C; ++t) m[t] = meta[j + t];
    ushort2 hv[C]; float zv[C];
    #pragma unroll
    for (int t = 0; t < C; ++t) {
        int c = __builtin_bit_cast(int, m[t].x);
        hv[t] = ((const ushort2*)(hb + (size_t)c * 128))[lane];
        zv[t] = zj[(size_t)c * 64 + lane];
    }
    #pragma unroll
    for (int t = 0; t < C; ++t) {
        float es = asr + m[t].y;
        acca.x += es * bf2f(hv[t].x);
        acca.y += es * bf2f(hv[t].y);
        zmax = fmaxf(zmax, zv[t]);
        vfsum += m[t].z;
    }
}

__global__ __launch_bounds__(256) void k_aggregate(
    const float4* __restrict__ meta, const int* __restrict__ rowptr,
    const float* __restrict__ h0, const unsigned short* __restrict__ hb,
    const float* __restrict__ zj,
    const float* __restrict__ a_self, const float* __restrict__ gpart,
    const float* __restrict__ Wg,
    const float* __restrict__ scale0, const float* __restrict__ offset0,
    const float* __restrict__ scale1, const float* __restrict__ offset1,
    float* __restrict__ out, int N) {
    int r = blockIdx.x * 4 + (threadIdx.x >> 6);
    int lane = threadIdx.x & 63;
    if (r >= N) return;
    int jb = rowptr[r], je = rowptr[r + 1];
    float2 acca = {0.f, 0.f};
    float zmax = -__builtin_inff();
    float vfsum = 0.f;
    float asr = a_self[r];
    int j = jb;
    while (j + 8 <= je) { agg_chunk<8>(meta, j, lane, asr, hb, zj, acca, zmax, vfsum); j += 8; }
    if (j + 4 <= je)    { agg_chunk<4>(meta, j, lane, asr, hb, zj, acca, zmax, vfsum); j += 4; }
    while (j < je)      { agg_chunk<1>(meta, j, lane, asr, hb, zj, acca, zmax, vfsum); j += 1; }
    if (jb == je) zmax = 0.f;  // empty segment: -inf -> 0
    float gs = zmax * Wg[128 + lane];
    #pragma unroll
    for (int off = 32; off; off >>= 1) gs += __shfl_xor(gs, off, 64);
    float gate = gpart[r] + gs + vfsum;  // all-f32 gate path (sign matters)
    float2 ag = {acca.x * gate, acca.y * gate};
    // BN on h0 row
    float2 x0 = ((const float2*)(h0 + (size_t)r * 128))[lane];
    float m0s = x0.x + x0.y;
    #pragma unroll
    for (int off = 32; off; off >>= 1) m0s += __shfl_xor(m0s, off, 64);
    float m0 = m0s * (1.f / 128.f);
    float d0x = x0.x - m0, d0y = x0.y - m0;
    float v0s = d0x * d0x + d0y * d0y;
    #pragma unroll
    for (int off = 32; off; off >>= 1) v0s += __shfl_xor(v0s, off, 64);
    float inv0 = rsqrtf(v0s * (1.f / 128.f) + 1e-9f);
    // BN on gated aggregation
    float m1s = ag.x + ag.y;
    #pragma unroll
    for (int off = 32; off; off >>= 1) m1s += __shfl_xor(m1s, off, 64);
    float m1 = m1s * (1.f / 128.f);
    float d1x = ag.x - m1, d1y = ag.y - m1;
    float v1s = d1x * d1x + d1y * d1y;
    #pragma unroll
    for (int off = 32; off; off >>= 1) v1s += __shfl_xor(v1s, off, 64);
    float inv1 = rsqrtf(v1s * (1.f / 128.f) + 1e-9f);
    float2 sc0 = ((const float2*)scale0)[lane], of0 = ((const float2*)offset0)[lane];
    float2 sc1 = ((const float2*)scale1)[lane], of1 = ((const float2*)offset1)[lane];
    float2 o;
    o.x = d0x * sc0.x * inv0 + of0.x + d1x * sc1.x * inv1 + of1.x;
    o.y = d0y * sc0.y * inv0 + of0.y + d1y * sc1.y * inv1 + of1.y;
    ((float2*)(out + (size_t)r * 128))[lane] = o;
}

extern "C" void kernel_launch(void* const* d_in, const int* in_sizes, int n_in,
                              void* d_out, int out_size, void* d_ws, size_t ws_size,
                              hipStream_t stream) {
    const int*   rows   = (const int*)d_in[0];
    const int*   cols   = (const int*)d_in[1];
    const float* vals   = (const float*)d_in[2];
    const float* feat   = (const float*)d_in[3];
    const float* W0     = (const float*)d_in[4];
    const float* b0     = (const float*)d_in[5];
    const float* W1     = (const float*)d_in[6];
    const float* b1     = (const float*)d_in[7];
    const float* att    = (const float*)d_in[8];
    const float* Wp     = (const float*)d_in[9];
    const float* Wg     = (const float*)d_in[10];
    const float* offset0 = (const float*)d_in[11];
    const float* scale0  = (const float*)d_in[12];
    const float* offset1 = (const float*)d_in[13];
    const float* scale1  = (const float*)d_in[14];
    float* out = (float*)d_out;

    const int E = in_sizes[0];
    const int N = in_sizes[3] / DIN;

    char* ws = (char*)d_ws;
    float* h0          = (float*)ws;          ws += (size_t)N * 128 * sizeof(float);
    unsigned short* hb = (unsigned short*)ws; ws += (size_t)N * 128 * sizeof(unsigned short);
    float* zj          = (float*)ws;          ws += (size_t)N * 64 * sizeof(float);
    float* a_self  = (float*)ws; ws += (size_t)N * sizeof(float);
    float* a_neigh = (float*)ws; ws += (size_t)N * sizeof(float);
    float* gpart   = (float*)ws; ws += (size_t)N * sizeof(float);
    float* fdotg   = (float*)ws; ws += (size_t)N * sizeof(float);
    int* deg      = (int*)ws; ws += (size_t)(N + 1) * sizeof(int);
    int* rowptr   = (int*)ws; ws += (size_t)(N + 1) * sizeof(int);
    int* bsum     = (int*)ws; ws += 64 * sizeof(int);
    int* boff     = (int*)ws; ws += 64 * sizeof(int);
    int* slot     = (int*)ws; ws += (size_t)E * sizeof(int);
    int2* cv      = (int2*)ws; ws += (size_t)E * sizeof(int2);
    ws = (char*)(((size_t)ws + 15) & ~(size_t)15);
    float4* meta  = (float4*)ws; ws += (size_t)E * sizeof(float4);

    hipMemsetAsync(deg, 0, (size_t)(N + 1) * sizeof(int), stream);

    k_deg<<<(E + 255) / 256, 256, 0, stream>>>(rows, deg, slot, E);
    int nb = (N + 1023) >> 10;  // 49 for N=50000; k_scan2 requires nb <= 64
    k_scan1<<<nb, 1024, 0, stream>>>(deg, rowptr, bsum, N);
    k_scan2<<<1, 64, 0, stream>>>(bsum, boff, rowptr, nb, N);
    k_scan3<<<(N + 255) / 256, 256, 0, stream>>>(rowptr, boff, N);
    k_scatter<<<(E + 255) / 256, 256, 0, stream>>>(rows, cols, vals, rowptr, slot, cv, E);

    int mt = (N + 127) / 128;
    dim3 gg(mt, 3);
    k_gemm3<<<gg, 256, 0, stream>>>(feat, W0, b0, W1, b1, Wp, att, Wg,
                                    h0, hb, zj, a_self, a_neigh, gpart, fdotg, N);

    k_edgemeta<<<(E + 255) / 256, 256, 0, stream>>>(cv, a_neigh, fdotg, meta, E);

    int nb4 = (N + 3) / 4;
    k_aggregate<<<nb4, 256, 0, stream>>>(meta, rowptr, h0, hb, zj,
                                         a_self, gpart, Wg,
                                         scale0, offset0, scale1, offset1, out, N);
}